// Round 17
// baseline (108.106 us; speedup 1.0000x reference)
//
#include <hip/hip_runtime.h>
#include <cstddef>
#include <cstdint>

#define M_TOK 21760
#define LQ_ 5440

typedef _Float16 f16x8 __attribute__((ext_vector_type(8)));
typedef _Float16 h2v __attribute__((ext_vector_type(2)));
typedef float f32x4v __attribute__((ext_vector_type(4)));
typedef _Float16 half4v __attribute__((ext_vector_type(4)));

__device__ __forceinline__ unsigned short f2h(float f) {
  return __builtin_bit_cast(unsigned short, (_Float16)f);
}
__device__ __forceinline__ float h2f(unsigned short u) {
  return (float)__builtin_bit_cast(_Float16, u);
}
__device__ __forceinline__ unsigned packh2(float a, float b) {
  h2v p; p[0] = (_Float16)a; p[1] = (_Float16)b;
  return __builtin_bit_cast(unsigned, p);
}

// ---------------------------------------------------------------------------
// prep_k: weights only — cast+transpose into G[n][k] f16 packed. 1408 blocks.
// ---------------------------------------------------------------------------
__global__ __launch_bounds__(256) void prep_k(
    const float* __restrict__ Wv, const float* __restrict__ Woff,
    const float* __restrict__ Wattn, const float* __restrict__ Wout,
    const float* __restrict__ W1, const float* __restrict__ W2,
    unsigned short* __restrict__ G)
{
  const int gid = blockIdx.x * 256 + threadIdx.x;
  const float* srcs[6] = {Wv, Woff, Wattn, Wout, W1, W2};
  const int starts[7] = {0, 65536, 131072, 163840, 229376, 294912, 360448};
  const int Nn[6] = {256, 256, 128, 256, 256, 256};
  int m = 0;
#pragma unroll
  for (int i = 1; i < 6; ++i) m += (gid >= starts[i]);
  const int local = gid - starts[m];
  const int n = local >> 8;
  const int k = local & 255;
  G[gid] = f2h(srcs[m][(size_t)k * Nn[m] + n]);
}

// ---------------------------------------------------------------------------
// Merged first-stage GEMM with FUSED f32->f16 A-staging (kills prep_x):
// 1D grid 850, XCD-aware swizzle (5 col-blocks of one m-tile on one XCD ->
// src/pos re-reads are L2-hits).  A tile: each thread loads 8 float4 of src
// (+pos for q-path), converts packed, ds_write_b128 into the SAME XOR-
// swizzled As layout the frag reads use. B via global_load_lds (unchanged).
//  by<2 : value = f16(src) @ WvT        -> value16
//  by>=2: fused = f16(src+pos) @ WfT    -> fused16
// ---------------------------------------------------------------------------
__global__ __launch_bounds__(256, 2) void gemm_qkv_k(
    const float* __restrict__ src, const float* __restrict__ pos,
    const unsigned short* __restrict__ WvT, const unsigned short* __restrict__ WfT,
    const float* __restrict__ bv, const float* __restrict__ boff,
    const float* __restrict__ battn,
    unsigned short* __restrict__ value16, unsigned short* __restrict__ fused16)
{
  const int id = blockIdx.x;
  const int xcd = id & 7;
  const int local = id >> 3;
  const int sid = xcd * 106 + min(xcd, 2) + local;
  const int bx = sid / 5;
  const int by = sid % 5;

  const bool isv = (by < 2);
  const unsigned short* Wt = isv ? WvT : WfT;
  const int n0 = isv ? by * 128 : (by - 2) * 128;
  const int N  = isv ? 256 : 384;
  unsigned short* out16 = isv ? value16 : fused16;
  const float* bsel; int nsub;
  if (isv)            { bsel = bv;    nsub = 0; }
  else if (n0 < 256)  { bsel = boff;  nsub = 0; }
  else                { bsel = battn; nsub = 256; }

  __shared__ unsigned short As[128 * 64];
  __shared__ unsigned short Bs[128 * 64];
  const int t = threadIdx.x;
  const int lane = t & 63, wave = t >> 6;
  const int wm = wave >> 1, wn = wave & 1;
  const int m0 = bx * 128;

  const int lrow = lane >> 3;
  const int pcol = (lane & 7) << 4;
  const int scol = pcol ^ (lrow << 4);

  // A-staging geometry: thread t handles row r = t>>1, f32 cols [ch, ch+32)
  const int ar = t >> 1;
  const int ach = (t & 1) * 32;
  const int aswz = (ar & 7) << 4;
  unsigned short* awr = As + ar * 64;   // row base (f16 elems)

  f32x4v acc[4][4];
#pragma unroll
  for (int i = 0; i < 4; ++i)
#pragma unroll
    for (int j = 0; j < 4; ++j) acc[i][j] = (f32x4v){0.f, 0.f, 0.f, 0.f};

  const int fr = lane & 15;
  const int fkb = (lane >> 4) << 4;

  for (int k0 = 0; k0 < 256; k0 += 64) {
    // ---- B tile via global_load_lds (unchanged) ----
#pragma unroll
    for (int i = 0; i < 4; ++i) {
      const int row = wave * 32 + i * 8 + lrow;
      const unsigned short* g = Wt + (size_t)(n0 + row) * 256 + k0 + (scol >> 1);
      unsigned short* s = Bs + (wave * 32 + i * 8) * 64;
      __builtin_amdgcn_global_load_lds(
          (const __attribute__((address_space(1))) void*)g,
          (__attribute__((address_space(3))) void*)s, 16, 0, 0);
    }
    // ---- A tile: f32 load + convert + swizzled ds_write ----
    {
      const float* sp = src + (size_t)(m0 + ar) * 256 + k0 + ach;
      float4 f[8];
#pragma unroll
      for (int j = 0; j < 8; ++j) f[j] = ((const float4*)sp)[j];
      if (!isv) {
        const float* pp = pos + (size_t)(m0 + ar) * 256 + k0 + ach;
#pragma unroll
        for (int j = 0; j < 8; ++j) {
          const float4 p4 = ((const float4*)pp)[j];
          f[j].x += p4.x; f[j].y += p4.y; f[j].z += p4.z; f[j].w += p4.w;
        }
      }
#pragma unroll
      for (int j = 0; j < 4; ++j) {
        uint4 u;
        u.x = packh2(f[j * 2].x, f[j * 2].y);
        u.y = packh2(f[j * 2].z, f[j * 2].w);
        u.z = packh2(f[j * 2 + 1].x, f[j * 2 + 1].y);
        u.w = packh2(f[j * 2 + 1].z, f[j * 2 + 1].w);
        const int colb = ((ach * 2) + j * 16) ^ aswz;
        *(uint4*)((char*)awr + colb) = u;
      }
    }
    __syncthreads();

    f16x8 af[4][2], bfr[4][2];
#pragma unroll
    for (int i = 0; i < 4; ++i) {
      const int row = wm * 64 + i * 16 + fr;
      const char* base = (const char*)As + row * 128;
#pragma unroll
      for (int kk = 0; kk < 2; ++kk)
        af[i][kk] = *(const f16x8*)(base + ((kk * 64 + fkb) ^ ((row & 7) << 4)));
    }
#pragma unroll
    for (int j = 0; j < 4; ++j) {
      const int row = wn * 64 + j * 16 + fr;
      const char* base = (const char*)Bs + row * 128;
#pragma unroll
      for (int kk = 0; kk < 2; ++kk)
        bfr[j][kk] = *(const f16x8*)(base + ((kk * 64 + fkb) ^ ((row & 7) << 4)));
    }
#pragma unroll
    for (int i = 0; i < 4; ++i)
#pragma unroll
      for (int j = 0; j < 4; ++j) {
        acc[i][j] = __builtin_amdgcn_mfma_f32_16x16x32_f16(af[i][0], bfr[j][0], acc[i][j], 0, 0, 0);
        acc[i][j] = __builtin_amdgcn_mfma_f32_16x16x32_f16(af[i][1], bfr[j][1], acc[i][j], 0, 0, 0);
      }
    __syncthreads();
  }

  const int fq = lane >> 4;
#pragma unroll
  for (int j = 0; j < 4; ++j) {
    const int n = n0 + wn * 64 + j * 16 + fr;
    const float bj = bsel[n - nsub];
#pragma unroll
    for (int i = 0; i < 4; ++i) {
#pragma unroll
      for (int r = 0; r < 4; ++r) {
        const int m = m0 + wm * 64 + i * 16 + fq * 4 + r;
        out16[(size_t)m * N + n] = f2h(acc[i][j][r] + bj);
      }
    }
  }
}

// ---------------------------------------------------------------------------
// Fused GEMM + residual + LayerNorm (Wout path). BM=32, BN=256, 512 thr.
// ---------------------------------------------------------------------------
__global__ __launch_bounds__(512, 4) void gemm_ln_k(
    const unsigned short* __restrict__ A, const unsigned short* __restrict__ Wt,
    const float* __restrict__ bias, const float* __restrict__ resf,
    const unsigned short* __restrict__ res16,
    const float* __restrict__ g, const float* __restrict__ b,
    float* __restrict__ outf, unsigned short* __restrict__ out16)
{
  __shared__ unsigned short As[32 * 64];
  __shared__ unsigned short Bs[256 * 64 + 288];
  const int t = threadIdx.x;
  const int lane = t & 63, wave = t >> 6;
  const int rt = wave & 1, cg = wave >> 1;
  const int m0 = blockIdx.x * 32;

  const int lrow = lane >> 3;
  const int pcol = (lane & 7) << 4;
  const int scol = pcol ^ (lrow << 4);

  f32x4v acc[4];
#pragma unroll
  for (int j = 0; j < 4; ++j) acc[j] = (f32x4v){0.f, 0.f, 0.f, 0.f};

  const int fr = lane & 15;
  const int fq = lane >> 4;
  const int fkb = fq << 4;

  for (int k0 = 0; k0 < 256; k0 += 64) {
    if (wave < 4) {
      const int row = wave * 8 + lrow;
      const unsigned short* gp = A + (size_t)(m0 + row) * 256 + k0 + (scol >> 1);
      unsigned short* s = As + (wave * 8) * 64;
      __builtin_amdgcn_global_load_lds(
          (const __attribute__((address_space(1))) void*)gp,
          (__attribute__((address_space(3))) void*)s, 16, 0, 0);
    }
#pragma unroll
    for (int i = 0; i < 4; ++i) {
      const int row = wave * 32 + i * 8 + lrow;
      const unsigned short* gp = Wt + (size_t)row * 256 + k0 + (scol >> 1);
      unsigned short* s = Bs + (wave * 32 + i * 8) * 64;
      __builtin_amdgcn_global_load_lds(
          (const __attribute__((address_space(1))) void*)gp,
          (__attribute__((address_space(3))) void*)s, 16, 0, 0);
    }
    __syncthreads();

    f16x8 af0, af1;
    {
      const int arow = rt * 16 + fr;
      const char* abase = (const char*)As + arow * 128;
      af0 = *(const f16x8*)(abase + ((0 + fkb) ^ ((arow & 7) << 4)));
      af1 = *(const f16x8*)(abase + ((64 + fkb) ^ ((arow & 7) << 4)));
    }
#pragma unroll
    for (int j = 0; j < 4; ++j) {
      const int brow = cg * 64 + j * 16 + fr;
      const char* bbase = (const char*)Bs + brow * 128;
      const f16x8 b0 = *(const f16x8*)(bbase + ((0 + fkb) ^ ((brow & 7) << 4)));
      const f16x8 b1 = *(const f16x8*)(bbase + ((64 + fkb) ^ ((brow & 7) << 4)));
      acc[j] = __builtin_amdgcn_mfma_f32_16x16x32_f16(af0, b0, acc[j], 0, 0, 0);
      acc[j] = __builtin_amdgcn_mfma_f32_16x16x32_f16(af1, b1, acc[j], 0, 0, 0);
    }
    __syncthreads();
  }

  float* Cs = (float*)Bs;
#pragma unroll
  for (int j = 0; j < 4; ++j) {
    const int col = cg * 64 + j * 16 + fr;
#pragma unroll
    for (int rr = 0; rr < 4; ++rr) {
      const int row = rt * 16 + fq * 4 + rr;
      Cs[row * 260 + col] = acc[j][rr];
    }
  }
  __syncthreads();

  const int lg = lane >> 4, li = lane & 15;
  const int row = wave * 4 + lg;
  const size_t rowoff = (size_t)(m0 + row) * 256;

  float4 v[4];
  float s = 0.f;
#pragma unroll
  for (int c4 = 0; c4 < 4; ++c4) {
    const int col = c4 * 64 + li * 4;
    float4 x = *(float4*)&Cs[row * 260 + col];
    const float4 bi = *(const float4*)&bias[col];
    float4 rv;
    if (resf) {
      rv = *(const float4*)&resf[rowoff + col];
    } else {
      const ushort4 r16 = *(const ushort4*)&res16[rowoff + col];
      rv.x = h2f(r16.x); rv.y = h2f(r16.y); rv.z = h2f(r16.z); rv.w = h2f(r16.w);
    }
    x.x += bi.x + rv.x; x.y += bi.y + rv.y;
    x.z += bi.z + rv.z; x.w += bi.w + rv.w;
    v[c4] = x;
    s += x.x + x.y + x.z + x.w;
  }
#pragma unroll
  for (int o = 1; o < 16; o <<= 1) s += __shfl_xor(s, o);
  const float mean = s * (1.f / 256.f);
  float ss = 0.f;
#pragma unroll
  for (int c4 = 0; c4 < 4; ++c4) {
    const float d0 = v[c4].x - mean, d1 = v[c4].y - mean;
    const float d2 = v[c4].z - mean, d3 = v[c4].w - mean;
    ss += d0 * d0 + d1 * d1 + d2 * d2 + d3 * d3;
  }
#pragma unroll
  for (int o = 1; o < 16; o <<= 1) ss += __shfl_xor(ss, o);
  const float rstd = rsqrtf(ss * (1.f / 256.f) + 1e-5f);

#pragma unroll
  for (int c4 = 0; c4 < 4; ++c4) {
    const int col = c4 * 64 + li * 4;
    const float4 gv = *(const float4*)&g[col];
    const float4 bv = *(const float4*)&b[col];
    float4 o4;
    o4.x = (v[c4].x - mean) * rstd * gv.x + bv.x;
    o4.y = (v[c4].y - mean) * rstd * gv.y + bv.y;
    o4.z = (v[c4].z - mean) * rstd * gv.z + bv.z;
    o4.w = (v[c4].w - mean) * rstd * gv.w + bv.w;
    if (outf) *(float4*)(outf + rowoff + col) = o4;
    if (out16) {
      ushort4 o;
      o.x = f2h(o4.x); o.y = f2h(o4.y); o.z = f2h(o4.z); o.w = f2h(o4.w);
      *(ushort4*)(out16 + rowoff + col) = o;
    }
  }
}

// ---------------------------------------------------------------------------
// Fused FFN: out = LN(relu(sxy@W1+bb1)@W2 + bb2 + sxy).  (R14 proven)
// ---------------------------------------------------------------------------
__global__ __launch_bounds__(512, 4) void gemm_ffn_ln_k(
    const unsigned short* __restrict__ sxy16,
    const unsigned short* __restrict__ W1T, const unsigned short* __restrict__ W2T,
    const float* __restrict__ bb1, const float* __restrict__ bb2,
    const float* __restrict__ g, const float* __restrict__ b,
    float* __restrict__ outf)
{
  __shared__ unsigned short Bs[256 * 64 + 288];
  __shared__ unsigned short Hs[32 * 264];
  const int t = threadIdx.x;
  const int lane = t & 63, wave = t >> 6;
  const int rt = wave & 1, cg = wave >> 1;
  const int m0 = blockIdx.x * 32;

  const int lrow = lane >> 3;
  const int pcol = (lane & 7) << 4;
  const int scol = pcol ^ (lrow << 4);

  const int fr = lane & 15;
  const int fq = lane >> 4;
  const int fkb = fq << 4;

  f32x4v acc[4];
#pragma unroll
  for (int j = 0; j < 4; ++j) acc[j] = (f32x4v){0.f, 0.f, 0.f, 0.f};

  for (int k0 = 0; k0 < 256; k0 += 64) {
#pragma unroll
    for (int i = 0; i < 4; ++i) {
      const int row = wave * 32 + i * 8 + lrow;
      const unsigned short* gp = W1T + (size_t)row * 256 + k0 + (scol >> 1);
      unsigned short* s = Bs + (wave * 32 + i * 8) * 64;
      __builtin_amdgcn_global_load_lds(
          (const __attribute__((address_space(1))) void*)gp,
          (__attribute__((address_space(3))) void*)s, 16, 0, 0);
    }
    const unsigned short* ap = sxy16 + (size_t)(m0 + rt * 16 + fr) * 256 + k0 + fq * 8;
    const f16x8 af0 = *(const f16x8*)ap;
    const f16x8 af1 = *(const f16x8*)(ap + 32);
    __syncthreads();
#pragma unroll
    for (int j = 0; j < 4; ++j) {
      const int brow = cg * 64 + j * 16 + fr;
      const char* bbase = (const char*)Bs + brow * 128;
      const f16x8 b0 = *(const f16x8*)(bbase + ((0 + fkb) ^ ((brow & 7) << 4)));
      const f16x8 b1 = *(const f16x8*)(bbase + ((64 + fkb) ^ ((brow & 7) << 4)));
      acc[j] = __builtin_amdgcn_mfma_f32_16x16x32_f16(af0, b0, acc[j], 0, 0, 0);
      acc[j] = __builtin_amdgcn_mfma_f32_16x16x32_f16(af1, b1, acc[j], 0, 0, 0);
    }
    __syncthreads();
  }

  {
    float b1j[4];
#pragma unroll
    for (int j = 0; j < 4; ++j) b1j[j] = bb1[cg * 64 + j * 16 + fr];
#pragma unroll
    for (int j = 0; j < 4; ++j) {
      const int col = cg * 64 + j * 16 + fr;
#pragma unroll
      for (int rr = 0; rr < 4; ++rr) {
        const int row = rt * 16 + fq * 4 + rr;
        Hs[row * 264 + col] = f2h(fmaxf(acc[j][rr] + b1j[j], 0.f));
      }
      acc[j] = (f32x4v){0.f, 0.f, 0.f, 0.f};
    }
  }
  __syncthreads();

  for (int k0 = 0; k0 < 256; k0 += 64) {
#pragma unroll
    for (int i = 0; i < 4; ++i) {
      const int row = wave * 32 + i * 8 + lrow;
      const unsigned short* gp = W2T + (size_t)row * 256 + k0 + (scol >> 1);
      unsigned short* s = Bs + (wave * 32 + i * 8) * 64;
      __builtin_amdgcn_global_load_lds(
          (const __attribute__((address_space(1))) void*)gp,
          (__attribute__((address_space(3))) void*)s, 16, 0, 0);
    }
    const int arow = rt * 16 + fr;
    const f16x8 af0 = *(const f16x8*)&Hs[arow * 264 + k0 + fq * 8];
    const f16x8 af1 = *(const f16x8*)&Hs[arow * 264 + k0 + fq * 8 + 32];
    __syncthreads();
#pragma unroll
    for (int j = 0; j < 4; ++j) {
      const int brow = cg * 64 + j * 16 + fr;
      const char* bbase = (const char*)Bs + brow * 128;
      const f16x8 b0 = *(const f16x8*)(bbase + ((0 + fkb) ^ ((brow & 7) << 4)));
      const f16x8 b1 = *(const f16x8*)(bbase + ((64 + fkb) ^ ((brow & 7) << 4)));
      acc[j] = __builtin_amdgcn_mfma_f32_16x16x32_f16(af0, b0, acc[j], 0, 0, 0);
      acc[j] = __builtin_amdgcn_mfma_f32_16x16x32_f16(af1, b1, acc[j], 0, 0, 0);
    }
    __syncthreads();
  }

  float* Cs = (float*)Bs;
#pragma unroll
  for (int j = 0; j < 4; ++j) {
    const int col = cg * 64 + j * 16 + fr;
#pragma unroll
    for (int rr = 0; rr < 4; ++rr) {
      const int row = rt * 16 + fq * 4 + rr;
      Cs[row * 260 + col] = acc[j][rr];
    }
  }
  __syncthreads();

  const int lg = lane >> 4, li = lane & 15;
  const int row = wave * 4 + lg;
  const size_t rowoff = (size_t)(m0 + row) * 256;

  float4 v[4];
  float s = 0.f;
#pragma unroll
  for (int c4 = 0; c4 < 4; ++c4) {
    const int col = c4 * 64 + li * 4;
    float4 x = *(float4*)&Cs[row * 260 + col];
    const float4 bi = *(const float4*)&bb2[col];
    const ushort4 r16 = *(const ushort4*)&sxy16[rowoff + col];
    x.x += bi.x + h2f(r16.x); x.y += bi.y + h2f(r16.y);
    x.z += bi.z + h2f(r16.z); x.w += bi.w + h2f(r16.w);
    v[c4] = x;
    s += x.x + x.y + x.z + x.w;
  }
#pragma unroll
  for (int o = 1; o < 16; o <<= 1) s += __shfl_xor(s, o);
  const float mean = s * (1.f / 256.f);
  float ss = 0.f;
#pragma unroll
  for (int c4 = 0; c4 < 4; ++c4) {
    const float d0 = v[c4].x - mean, d1 = v[c4].y - mean;
    const float d2 = v[c4].z - mean, d3 = v[c4].w - mean;
    ss += d0 * d0 + d1 * d1 + d2 * d2 + d3 * d3;
  }
#pragma unroll
  for (int o = 1; o < 16; o <<= 1) ss += __shfl_xor(ss, o);
  const float rstd = rsqrtf(ss * (1.f / 256.f) + 1e-5f);

#pragma unroll
  for (int c4 = 0; c4 < 4; ++c4) {
    const int col = c4 * 64 + li * 4;
    const float4 gv = *(const float4*)&g[col];
    const float4 bv = *(const float4*)&b[col];
    float4 o4;
    o4.x = (v[c4].x - mean) * rstd * gv.x + bv.x;
    o4.y = (v[c4].y - mean) * rstd * gv.y + bv.y;
    o4.z = (v[c4].z - mean) * rstd * gv.z + bv.z;
    o4.w = (v[c4].w - mean) * rstd * gv.w + bv.w;
    *(float4*)(outf + rowoff + col) = o4;
  }
}

// ---------------------------------------------------------------------------
// Deformable sampling v5 (frozen since R8 — best measured 39.5-39.7us).
// ---------------------------------------------------------------------------
__global__ __launch_bounds__(256) void samp_k(
    const unsigned short* __restrict__ value16, const unsigned short* __restrict__ fused16,
    const float* __restrict__ ref, unsigned short* __restrict__ att16)
{
  const int b = blockIdx.x;
  const int wg = (b & 7) * 340 + (b >> 3);
  const int tok0 = wg * 8;

  __shared__ half4v swv[8][136];
  __shared__ uint2  siv[8][136];
  const int t = threadIdx.x;
  const _Float16* fh = (const _Float16*)fused16;

#pragma unroll
  for (int it = 0; it < 4; ++it) {
    const int idx = it * 256 + t;
    const int ti = idx >> 7;
    const int e  = idx & 127;
    const int tok = tok0 + ti;
    const int h = e >> 4;
    const int lvl = (e >> 2) & 3;
    const int HW[4] = {64, 32, 16, 8};
    const int LS[4] = {0, 4096, 5120, 5376};
    const int Wl = HW[lvl];

    const float lg = (float)fh[(size_t)tok * 384 + 256 + e];
    float mx = lg;
#pragma unroll
    for (int o = 1; o < 16; o <<= 1) mx = fmaxf(mx, __shfl_xor(mx, o, 16));
    const float ex = __expf(lg - mx);
    float sm = ex;
#pragma unroll
    for (int o = 1; o < 16; o <<= 1) sm += __shfl_xor(sm, o, 16);
    const float a = ex / sm;

    const float ox = (float)fh[(size_t)tok * 384 + e * 2 + 0];
    const float oy = (float)fh[(size_t)tok * 384 + e * 2 + 1];
    const float rx = ref[(size_t)tok * 8 + lvl * 2 + 0];
    const float ry = ref[(size_t)tok * 8 + lvl * 2 + 1];
    const float x = rx * (float)Wl + ox - 0.5f;
    const float y = ry * (float)Wl + oy - 0.5f;
    const float x0f = floorf(x), y0f = floorf(y);
    const float fx = x - x0f, fy = y - y0f;
    const int x0 = (int)x0f, y0 = (int)y0f;

    const int xi1 = x0 + 1, yi1 = y0 + 1;
    const float wx0 = 1.f - fx, wx1 = fx, wy0 = 1.f - fy, wy1 = fy;
    const int xc0 = min(max(x0, 0), Wl - 1), xc1 = min(max(xi1, 0), Wl - 1);
    const int yc0 = min(max(y0, 0), Wl - 1), yc1 = min(max(yi1, 0), Wl - 1);
    const bool vx0 = (x0 >= 0) & (x0 < Wl), vx1 = (xi1 >= 0) & (xi1 < Wl);
    const bool vy0 = (y0 >= 0) & (y0 < Wl), vy1 = (yi1 >= 0) & (yi1 < Wl);
    half4v hw;
    hw.x = (_Float16)((vx0 & vy0) ? a * wx0 * wy0 : 0.f);
    hw.y = (_Float16)((vx1 & vy0) ? a * wx1 * wy0 : 0.f);
    hw.z = (_Float16)((vx0 & vy1) ? a * wx0 * wy1 : 0.f);
    hw.w = (_Float16)((vx1 & vy1) ? a * wx1 * wy1 : 0.f);
    const unsigned i00 = (unsigned)(LS[lvl] + yc0 * Wl + xc0);
    const unsigned i01 = (unsigned)(LS[lvl] + yc0 * Wl + xc1);
    const unsigned i10 = (unsigned)(LS[lvl] + yc1 * Wl + xc0);
    const unsigned i11 = (unsigned)(LS[lvl] + yc1 * Wl + xc1);
    uint2 io;
    io.x = i00 | (i01 << 16);
    io.y = i10 | (i11 << 16);
    const int sl = e + h;
    swv[ti][sl] = hw;
    siv[ti][sl] = io;
  }
  __syncthreads();

  const int wave = t >> 6, lane = t & 63;
  const int ti = wave * 2 + (lane >> 5);
  const int h = (lane >> 2) & 7, dg = lane & 3;
  const int tok = tok0 + ti;
  const int vbase = (tok0 / LQ_) * LQ_;
  const char* vb = (const char*)(value16 + (size_t)vbase * 256);
  const int laneoff = h * 64 + dg * 16;
  h2v a0 = {0, 0}, a1 = {0, 0}, a2 = {0, 0}, a3 = {0, 0};
  const int ebase = h * 17;

#pragma unroll 4
  for (int p = 0; p < 16; ++p) {
    const half4v hw = swv[ti][ebase + p];
    const uint2 io = siv[ti][ebase + p];
    const int o00 = (int)((io.x & 0xFFFFu) << 9) + laneoff;
    const int o01 = (int)((io.x >> 16) << 9) + laneoff;
    const int o10 = (int)((io.y & 0xFFFFu) << 9) + laneoff;
    const int o11 = (int)((io.y >> 16) << 9) + laneoff;
    const uint4 u0 = *(const uint4*)(vb + o00);
    const uint4 u1 = *(const uint4*)(vb + o01);
    const uint4 u2 = *(const uint4*)(vb + o10);
    const uint4 u3 = *(const uint4*)(vb + o11);
#define CORNER(U, WI) {                                            \
    const h2v w2 = __builtin_shufflevector(hw, hw, WI, WI);        \
    a0 += w2 * __builtin_bit_cast(h2v, U.x);                       \
    a1 += w2 * __builtin_bit_cast(h2v, U.y);                       \
    a2 += w2 * __builtin_bit_cast(h2v, U.z);                       \
    a3 += w2 * __builtin_bit_cast(h2v, U.w); }
    CORNER(u0, 0) CORNER(u1, 1) CORNER(u2, 2) CORNER(u3, 3)
#undef CORNER
  }

  uint4 o;
  o.x = __builtin_bit_cast(unsigned, a0);
  o.y = __builtin_bit_cast(unsigned, a1);
  o.z = __builtin_bit_cast(unsigned, a2);
  o.w = __builtin_bit_cast(unsigned, a3);
  *(uint4*)(att16 + (size_t)tok * 256 + h * 32 + dg * 8) = o;
}

// ---------------------------------------------------------------------------
extern "C" void kernel_launch(void* const* d_in, const int* in_sizes, int n_in,
                              void* d_out, int out_size, void* d_ws, size_t ws_size,
                              hipStream_t stream)
{
  const float* src   = (const float*)d_in[0];
  const float* pos   = (const float*)d_in[1];
  const float* ref   = (const float*)d_in[2];
  const float* Wv    = (const float*)d_in[5];
  const float* bv    = (const float*)d_in[6];
  const float* Woff  = (const float*)d_in[7];
  const float* boff  = (const float*)d_in[8];
  const float* Wattn = (const float*)d_in[9];
  const float* battn = (const float*)d_in[10];
  const float* Wout  = (const float*)d_in[11];
  const float* bout  = (const float*)d_in[12];
  const float* g1    = (const float*)d_in[13];
  const float* b1    = (const float*)d_in[14];
  const float* W1    = (const float*)d_in[15];
  const float* bb1   = (const float*)d_in[16];
  const float* W2    = (const float*)d_in[17];
  const float* bb2   = (const float*)d_in[18];
  const float* g3    = (const float*)d_in[19];
  const float* b3    = (const float*)d_in[20];

  float* out = (float*)d_out;
  char* ws = (char*)d_ws;
  const size_t M = M_TOK;

  unsigned short* value16 = (unsigned short*)ws;         // f16 M*256 (ends at samp)
  unsigned short* fused16 = (unsigned short*)(ws + M * 256 * 4);  // f16 M*384
  unsigned short* bufE = fused16 + M * 384;              // f16 M*256: att16
  unsigned short* bufF = bufE + M * 256;                 // f16 M*256: sxy16
  unsigned short* bufG = bufF + M * 256;                 // f16 weights (360448)

  unsigned short* WvT     = bufG + 0;
  unsigned short* WfusedT = bufG + 65536;
  unsigned short* WoutT   = bufG + 163840;
  unsigned short* W1T     = bufG + 229376;
  unsigned short* W2T     = bufG + 294912;

  const dim3 blk(256);

  // weights only
  prep_k<<<dim3(1408), blk, 0, stream>>>(Wv, Woff, Wattn, Wout, W1, W2, bufG);
  // value16 = f16(src)@WvT+bv ; fused16 = f16(src+pos)@[Woff|Wattn]+[boff|battn]
  gemm_qkv_k<<<dim3(850), blk, 0, stream>>>(src, pos, WvT, WfusedT,
                                            bv, boff, battn, value16, fused16);
  // sampling (with in-kernel softmax) -> att16
  samp_k<<<dim3(2720), blk, 0, stream>>>(value16, fused16, ref, bufE);
  // sxy16 = f16(LN(att @ Wout + bout + src))
  gemm_ln_k<<<dim3(680), dim3(512), 0, stream>>>(bufE, WoutT, bout, src, nullptr,
                                                 g1, b1, nullptr, bufF);
  // out = LN(relu(sxy@W1+bb1)@W2 + bb2 + sxy)   [fused FFN]
  gemm_ffn_ln_k<<<dim3(680), dim3(512), 0, stream>>>(bufF, W1T, W2T, bb1, bb2,
                                                     g3, b3, out);
}

// Round 18
// 99.282 us; speedup vs baseline: 1.0889x; 1.0889x over previous
//
#include <hip/hip_runtime.h>
#include <cstddef>
#include <cstdint>

#define M_TOK 21760
#define LQ_ 5440

typedef _Float16 f16x8 __attribute__((ext_vector_type(8)));
typedef _Float16 h2v __attribute__((ext_vector_type(2)));
typedef float f32x4v __attribute__((ext_vector_type(4)));
typedef _Float16 half4v __attribute__((ext_vector_type(4)));

__device__ __forceinline__ unsigned short f2h(float f) {
  return __builtin_bit_cast(unsigned short, (_Float16)f);
}
__device__ __forceinline__ float h2f(unsigned short u) {
  return (float)__builtin_bit_cast(_Float16, u);
}

// ---------------------------------------------------------------------------
// prep_k: blocks [0,5440): s16 = f16(src), q16 = f16(src+pos)
//         blocks [5440,6848): cast+transpose weights into G[n][k] f16 packed
// ---------------------------------------------------------------------------
__global__ __launch_bounds__(256) void prep_k(
    const float* __restrict__ src, const float* __restrict__ pos,
    const float* __restrict__ Wv, const float* __restrict__ Woff,
    const float* __restrict__ Wattn, const float* __restrict__ Wout,
    const float* __restrict__ W1, const float* __restrict__ W2,
    unsigned short* __restrict__ s16, unsigned short* __restrict__ q16,
    unsigned short* __restrict__ G)
{
  const int b = blockIdx.x;
  if (b < 5440) {
    const int i = b * 256 + threadIdx.x;
    const float4 s = ((const float4*)src)[i];
    const float4 p = ((const float4*)pos)[i];
    ushort4 a, q;
    a.x = f2h(s.x); a.y = f2h(s.y); a.z = f2h(s.z); a.w = f2h(s.w);
    q.x = f2h(s.x + p.x); q.y = f2h(s.y + p.y); q.z = f2h(s.z + p.z); q.w = f2h(s.w + p.w);
    ((ushort4*)s16)[i] = a;
    ((ushort4*)q16)[i] = q;
  } else {
    const int gid = (b - 5440) * 256 + threadIdx.x;
    const float* srcs[6] = {Wv, Woff, Wattn, Wout, W1, W2};
    const int starts[7] = {0, 65536, 131072, 163840, 229376, 294912, 360448};
    const int Nn[6] = {256, 256, 128, 256, 256, 256};
    int m = 0;
#pragma unroll
    for (int i = 1; i < 6; ++i) m += (gid >= starts[i]);
    const int local = gid - starts[m];
    const int n = local >> 8;
    const int k = local & 255;
    G[gid] = f2h(srcs[m][(size_t)k * Nn[m] + n]);
  }
}

// ---------------------------------------------------------------------------
// Merged first-stage GEMM, 1D grid 850 with XCD-aware swizzle.
// __launch_bounds__(256,3) -> 12 waves/CU (3 blocks) for latency hiding.
// ---------------------------------------------------------------------------
__global__ __launch_bounds__(256, 3) void gemm_qkv_k(
    const unsigned short* __restrict__ s16, const unsigned short* __restrict__ q16,
    const unsigned short* __restrict__ WvT, const unsigned short* __restrict__ WfT,
    const float* __restrict__ bv, const float* __restrict__ boff,
    const float* __restrict__ battn,
    unsigned short* __restrict__ value16, unsigned short* __restrict__ fused16)
{
  const int id = blockIdx.x;
  const int xcd = id & 7;
  const int local = id >> 3;
  const int sid = xcd * 106 + min(xcd, 2) + local;
  const int bx = sid / 5;
  const int by = sid % 5;

  const bool isv = (by < 2);
  const unsigned short* A  = isv ? s16 : q16;
  const unsigned short* Wt = isv ? WvT : WfT;
  const int n0 = isv ? by * 128 : (by - 2) * 128;
  const int N  = isv ? 256 : 384;
  unsigned short* out16 = isv ? value16 : fused16;
  const float* bsel; int nsub;
  if (isv)            { bsel = bv;    nsub = 0; }
  else if (n0 < 256)  { bsel = boff;  nsub = 0; }
  else                { bsel = battn; nsub = 256; }

  __shared__ unsigned short As[128 * 64];
  __shared__ unsigned short Bs[128 * 64];
  const int t = threadIdx.x;
  const int lane = t & 63, wave = t >> 6;
  const int wm = wave >> 1, wn = wave & 1;
  const int m0 = bx * 128;

  const int lrow = lane >> 3;
  const int pcol = (lane & 7) << 4;
  const int scol = pcol ^ (lrow << 4);

  f32x4v acc[4][4];
#pragma unroll
  for (int i = 0; i < 4; ++i)
#pragma unroll
    for (int j = 0; j < 4; ++j) acc[i][j] = (f32x4v){0.f, 0.f, 0.f, 0.f};

  const int fr = lane & 15;
  const int fkb = (lane >> 4) << 4;

  for (int k0 = 0; k0 < 256; k0 += 64) {
#pragma unroll
    for (int i = 0; i < 4; ++i) {
      const int row = wave * 32 + i * 8 + lrow;
      const unsigned short* g = A + (size_t)(m0 + row) * 256 + k0 + (scol >> 1);
      unsigned short* s = As + (wave * 32 + i * 8) * 64;
      __builtin_amdgcn_global_load_lds(
          (const __attribute__((address_space(1))) void*)g,
          (__attribute__((address_space(3))) void*)s, 16, 0, 0);
    }
#pragma unroll
    for (int i = 0; i < 4; ++i) {
      const int row = wave * 32 + i * 8 + lrow;
      const unsigned short* g = Wt + (size_t)(n0 + row) * 256 + k0 + (scol >> 1);
      unsigned short* s = Bs + (wave * 32 + i * 8) * 64;
      __builtin_amdgcn_global_load_lds(
          (const __attribute__((address_space(1))) void*)g,
          (__attribute__((address_space(3))) void*)s, 16, 0, 0);
    }
    __syncthreads();

    f16x8 af[4][2], bfr[4][2];
#pragma unroll
    for (int i = 0; i < 4; ++i) {
      const int row = wm * 64 + i * 16 + fr;
      const char* base = (const char*)As + row * 128;
#pragma unroll
      for (int kk = 0; kk < 2; ++kk)
        af[i][kk] = *(const f16x8*)(base + ((kk * 64 + fkb) ^ ((row & 7) << 4)));
    }
#pragma unroll
    for (int j = 0; j < 4; ++j) {
      const int row = wn * 64 + j * 16 + fr;
      const char* base = (const char*)Bs + row * 128;
#pragma unroll
      for (int kk = 0; kk < 2; ++kk)
        bfr[j][kk] = *(const f16x8*)(base + ((kk * 64 + fkb) ^ ((row & 7) << 4)));
    }
#pragma unroll
    for (int i = 0; i < 4; ++i)
#pragma unroll
      for (int j = 0; j < 4; ++j) {
        acc[i][j] = __builtin_amdgcn_mfma_f32_16x16x32_f16(af[i][0], bfr[j][0], acc[i][j], 0, 0, 0);
        acc[i][j] = __builtin_amdgcn_mfma_f32_16x16x32_f16(af[i][1], bfr[j][1], acc[i][j], 0, 0, 0);
      }
    __syncthreads();
  }

  const int fq = lane >> 4;
#pragma unroll
  for (int j = 0; j < 4; ++j) {
    const int n = n0 + wn * 64 + j * 16 + fr;
    const float bj = bsel[n - nsub];
#pragma unroll
    for (int i = 0; i < 4; ++i) {
#pragma unroll
      for (int r = 0; r < 4; ++r) {
        const int m = m0 + wm * 64 + i * 16 + fq * 4 + r;
        out16[(size_t)m * N + n] = f2h(acc[i][j][r] + bj);
      }
    }
  }
}

// ---------------------------------------------------------------------------
// Fused GEMM + residual + LayerNorm (Wout path). BM=32, BN=256, 512 thr.
// ---------------------------------------------------------------------------
__global__ __launch_bounds__(512, 4) void gemm_ln_k(
    const unsigned short* __restrict__ A, const unsigned short* __restrict__ Wt,
    const float* __restrict__ bias, const float* __restrict__ resf,
    const unsigned short* __restrict__ res16,
    const float* __restrict__ g, const float* __restrict__ b,
    float* __restrict__ outf, unsigned short* __restrict__ out16)
{
  __shared__ unsigned short As[32 * 64];
  __shared__ unsigned short Bs[256 * 64 + 288];
  const int t = threadIdx.x;
  const int lane = t & 63, wave = t >> 6;
  const int rt = wave & 1, cg = wave >> 1;
  const int m0 = blockIdx.x * 32;

  const int lrow = lane >> 3;
  const int pcol = (lane & 7) << 4;
  const int scol = pcol ^ (lrow << 4);

  f32x4v acc[4];
#pragma unroll
  for (int j = 0; j < 4; ++j) acc[j] = (f32x4v){0.f, 0.f, 0.f, 0.f};

  const int fr = lane & 15;
  const int fq = lane >> 4;
  const int fkb = fq << 4;

  for (int k0 = 0; k0 < 256; k0 += 64) {
    if (wave < 4) {
      const int row = wave * 8 + lrow;
      const unsigned short* gp = A + (size_t)(m0 + row) * 256 + k0 + (scol >> 1);
      unsigned short* s = As + (wave * 8) * 64;
      __builtin_amdgcn_global_load_lds(
          (const __attribute__((address_space(1))) void*)gp,
          (__attribute__((address_space(3))) void*)s, 16, 0, 0);
    }
#pragma unroll
    for (int i = 0; i < 4; ++i) {
      const int row = wave * 32 + i * 8 + lrow;
      const unsigned short* gp = Wt + (size_t)row * 256 + k0 + (scol >> 1);
      unsigned short* s = Bs + (wave * 32 + i * 8) * 64;
      __builtin_amdgcn_global_load_lds(
          (const __attribute__((address_space(1))) void*)gp,
          (__attribute__((address_space(3))) void*)s, 16, 0, 0);
    }
    __syncthreads();

    f16x8 af0, af1;
    {
      const int arow = rt * 16 + fr;
      const char* abase = (const char*)As + arow * 128;
      af0 = *(const f16x8*)(abase + ((0 + fkb) ^ ((arow & 7) << 4)));
      af1 = *(const f16x8*)(abase + ((64 + fkb) ^ ((arow & 7) << 4)));
    }
#pragma unroll
    for (int j = 0; j < 4; ++j) {
      const int brow = cg * 64 + j * 16 + fr;
      const char* bbase = (const char*)Bs + brow * 128;
      const f16x8 b0 = *(const f16x8*)(bbase + ((0 + fkb) ^ ((brow & 7) << 4)));
      const f16x8 b1 = *(const f16x8*)(bbase + ((64 + fkb) ^ ((brow & 7) << 4)));
      acc[j] = __builtin_amdgcn_mfma_f32_16x16x32_f16(af0, b0, acc[j], 0, 0, 0);
      acc[j] = __builtin_amdgcn_mfma_f32_16x16x32_f16(af1, b1, acc[j], 0, 0, 0);
    }
    __syncthreads();
  }

  float* Cs = (float*)Bs;
#pragma unroll
  for (int j = 0; j < 4; ++j) {
    const int col = cg * 64 + j * 16 + fr;
#pragma unroll
    for (int rr = 0; rr < 4; ++rr) {
      const int row = rt * 16 + fq * 4 + rr;
      Cs[row * 260 + col] = acc[j][rr];
    }
  }
  __syncthreads();

  const int lg = lane >> 4, li = lane & 15;
  const int row = wave * 4 + lg;
  const size_t rowoff = (size_t)(m0 + row) * 256;

  float4 v[4];
  float s = 0.f;
#pragma unroll
  for (int c4 = 0; c4 < 4; ++c4) {
    const int col = c4 * 64 + li * 4;
    float4 x = *(float4*)&Cs[row * 260 + col];
    const float4 bi = *(const float4*)&bias[col];
    float4 rv;
    if (resf) {
      rv = *(const float4*)&resf[rowoff + col];
    } else {
      const ushort4 r16 = *(const ushort4*)&res16[rowoff + col];
      rv.x = h2f(r16.x); rv.y = h2f(r16.y); rv.z = h2f(r16.z); rv.w = h2f(r16.w);
    }
    x.x += bi.x + rv.x; x.y += bi.y + rv.y;
    x.z += bi.z + rv.z; x.w += bi.w + rv.w;
    v[c4] = x;
    s += x.x + x.y + x.z + x.w;
  }
#pragma unroll
  for (int o = 1; o < 16; o <<= 1) s += __shfl_xor(s, o);
  const float mean = s * (1.f / 256.f);
  float ss = 0.f;
#pragma unroll
  for (int c4 = 0; c4 < 4; ++c4) {
    const float d0 = v[c4].x - mean, d1 = v[c4].y - mean;
    const float d2 = v[c4].z - mean, d3 = v[c4].w - mean;
    ss += d0 * d0 + d1 * d1 + d2 * d2 + d3 * d3;
  }
#pragma unroll
  for (int o = 1; o < 16; o <<= 1) ss += __shfl_xor(ss, o);
  const float rstd = rsqrtf(ss * (1.f / 256.f) + 1e-5f);

#pragma unroll
  for (int c4 = 0; c4 < 4; ++c4) {
    const int col = c4 * 64 + li * 4;
    const float4 gv = *(const float4*)&g[col];
    const float4 bv = *(const float4*)&b[col];
    float4 o4;
    o4.x = (v[c4].x - mean) * rstd * gv.x + bv.x;
    o4.y = (v[c4].y - mean) * rstd * gv.y + bv.y;
    o4.z = (v[c4].z - mean) * rstd * gv.z + bv.z;
    o4.w = (v[c4].w - mean) * rstd * gv.w + bv.w;
    if (outf) *(float4*)(outf + rowoff + col) = o4;
    if (out16) {
      ushort4 o;
      o.x = f2h(o4.x); o.y = f2h(o4.y); o.z = f2h(o4.z); o.w = f2h(o4.w);
      *(ushort4*)(out16 + rowoff + col) = o;
    }
  }
}

// ---------------------------------------------------------------------------
// Fused FFN: out = LN(relu(sxy@W1+bb1)@W2 + bb2 + sxy).
// ---------------------------------------------------------------------------
__global__ __launch_bounds__(512, 4) void gemm_ffn_ln_k(
    const unsigned short* __restrict__ sxy16,
    const unsigned short* __restrict__ W1T, const unsigned short* __restrict__ W2T,
    const float* __restrict__ bb1, const float* __restrict__ bb2,
    const float* __restrict__ g, const float* __restrict__ b,
    float* __restrict__ outf)
{
  __shared__ unsigned short Bs[256 * 64 + 288];
  __shared__ unsigned short Hs[32 * 264];
  const int t = threadIdx.x;
  const int lane = t & 63, wave = t >> 6;
  const int rt = wave & 1, cg = wave >> 1;
  const int m0 = blockIdx.x * 32;

  const int lrow = lane >> 3;
  const int pcol = (lane & 7) << 4;
  const int scol = pcol ^ (lrow << 4);

  const int fr = lane & 15;
  const int fq = lane >> 4;
  const int fkb = fq << 4;

  f32x4v acc[4];
#pragma unroll
  for (int j = 0; j < 4; ++j) acc[j] = (f32x4v){0.f, 0.f, 0.f, 0.f};

  for (int k0 = 0; k0 < 256; k0 += 64) {
#pragma unroll
    for (int i = 0; i < 4; ++i) {
      const int row = wave * 32 + i * 8 + lrow;
      const unsigned short* gp = W1T + (size_t)row * 256 + k0 + (scol >> 1);
      unsigned short* s = Bs + (wave * 32 + i * 8) * 64;
      __builtin_amdgcn_global_load_lds(
          (const __attribute__((address_space(1))) void*)gp,
          (__attribute__((address_space(3))) void*)s, 16, 0, 0);
    }
    const unsigned short* ap = sxy16 + (size_t)(m0 + rt * 16 + fr) * 256 + k0 + fq * 8;
    const f16x8 af0 = *(const f16x8*)ap;
    const f16x8 af1 = *(const f16x8*)(ap + 32);
    __syncthreads();
#pragma unroll
    for (int j = 0; j < 4; ++j) {
      const int brow = cg * 64 + j * 16 + fr;
      const char* bbase = (const char*)Bs + brow * 128;
      const f16x8 b0 = *(const f16x8*)(bbase + ((0 + fkb) ^ ((brow & 7) << 4)));
      const f16x8 b1 = *(const f16x8*)(bbase + ((64 + fkb) ^ ((brow & 7) << 4)));
      acc[j] = __builtin_amdgcn_mfma_f32_16x16x32_f16(af0, b0, acc[j], 0, 0, 0);
      acc[j] = __builtin_amdgcn_mfma_f32_16x16x32_f16(af1, b1, acc[j], 0, 0, 0);
    }
    __syncthreads();
  }

  {
    float b1j[4];
#pragma unroll
    for (int j = 0; j < 4; ++j) b1j[j] = bb1[cg * 64 + j * 16 + fr];
#pragma unroll
    for (int j = 0; j < 4; ++j) {
      const int col = cg * 64 + j * 16 + fr;
#pragma unroll
      for (int rr = 0; rr < 4; ++rr) {
        const int row = rt * 16 + fq * 4 + rr;
        Hs[row * 264 + col] = f2h(fmaxf(acc[j][rr] + b1j[j], 0.f));
      }
      acc[j] = (f32x4v){0.f, 0.f, 0.f, 0.f};
    }
  }
  __syncthreads();

  for (int k0 = 0; k0 < 256; k0 += 64) {
#pragma unroll
    for (int i = 0; i < 4; ++i) {
      const int row = wave * 32 + i * 8 + lrow;
      const unsigned short* gp = W2T + (size_t)row * 256 + k0 + (scol >> 1);
      unsigned short* s = Bs + (wave * 32 + i * 8) * 64;
      __builtin_amdgcn_global_load_lds(
          (const __attribute__((address_space(1))) void*)gp,
          (__attribute__((address_space(3))) void*)s, 16, 0, 0);
    }
    const int arow = rt * 16 + fr;
    const f16x8 af0 = *(const f16x8*)&Hs[arow * 264 + k0 + fq * 8];
    const f16x8 af1 = *(const f16x8*)&Hs[arow * 264 + k0 + fq * 8 + 32];
    __syncthreads();
#pragma unroll
    for (int j = 0; j < 4; ++j) {
      const int brow = cg * 64 + j * 16 + fr;
      const char* bbase = (const char*)Bs + brow * 128;
      const f16x8 b0 = *(const f16x8*)(bbase + ((0 + fkb) ^ ((brow & 7) << 4)));
      const f16x8 b1 = *(const f16x8*)(bbase + ((64 + fkb) ^ ((brow & 7) << 4)));
      acc[j] = __builtin_amdgcn_mfma_f32_16x16x32_f16(af0, b0, acc[j], 0, 0, 0);
      acc[j] = __builtin_amdgcn_mfma_f32_16x16x32_f16(af1, b1, acc[j], 0, 0, 0);
    }
    __syncthreads();
  }

  float* Cs = (float*)Bs;
#pragma unroll
  for (int j = 0; j < 4; ++j) {
    const int col = cg * 64 + j * 16 + fr;
#pragma unroll
    for (int rr = 0; rr < 4; ++rr) {
      const int row = rt * 16 + fq * 4 + rr;
      Cs[row * 260 + col] = acc[j][rr];
    }
  }
  __syncthreads();

  const int lg = lane >> 4, li = lane & 15;
  const int row = wave * 4 + lg;
  const size_t rowoff = (size_t)(m0 + row) * 256;

  float4 v[4];
  float s = 0.f;
#pragma unroll
  for (int c4 = 0; c4 < 4; ++c4) {
    const int col = c4 * 64 + li * 4;
    float4 x = *(float4*)&Cs[row * 260 + col];
    const float4 bi = *(const float4*)&bb2[col];
    const ushort4 r16 = *(const ushort4*)&sxy16[rowoff + col];
    x.x += bi.x + h2f(r16.x); x.y += bi.y + h2f(r16.y);
    x.z += bi.z + h2f(r16.z); x.w += bi.w + h2f(r16.w);
    v[c4] = x;
    s += x.x + x.y + x.z + x.w;
  }
#pragma unroll
  for (int o = 1; o < 16; o <<= 1) s += __shfl_xor(s, o);
  const float mean = s * (1.f / 256.f);
  float ss = 0.f;
#pragma unroll
  for (int c4 = 0; c4 < 4; ++c4) {
    const float d0 = v[c4].x - mean, d1 = v[c4].y - mean;
    const float d2 = v[c4].z - mean, d3 = v[c4].w - mean;
    ss += d0 * d0 + d1 * d1 + d2 * d2 + d3 * d3;
  }
#pragma unroll
  for (int o = 1; o < 16; o <<= 1) ss += __shfl_xor(ss, o);
  const float rstd = rsqrtf(ss * (1.f / 256.f) + 1e-5f);

#pragma unroll
  for (int c4 = 0; c4 < 4; ++c4) {
    const int col = c4 * 64 + li * 4;
    const float4 gv = *(const float4*)&g[col];
    const float4 bv = *(const float4*)&b[col];
    float4 o4;
    o4.x = (v[c4].x - mean) * rstd * gv.x + bv.x;
    o4.y = (v[c4].y - mean) * rstd * gv.y + bv.y;
    o4.z = (v[c4].z - mean) * rstd * gv.z + bv.z;
    o4.w = (v[c4].w - mean) * rstd * gv.w + bv.w;
    *(float4*)(outf + rowoff + col) = o4;
  }
}

// ---------------------------------------------------------------------------
// Deformable sampling v5 (frozen since R8 — best measured 39.5-39.7us).
// ---------------------------------------------------------------------------
__global__ __launch_bounds__(256) void samp_k(
    const unsigned short* __restrict__ value16, const unsigned short* __restrict__ fused16,
    const float* __restrict__ ref, unsigned short* __restrict__ att16)
{
  const int b = blockIdx.x;
  const int wg = (b & 7) * 340 + (b >> 3);
  const int tok0 = wg * 8;

  __shared__ half4v swv[8][136];
  __shared__ uint2  siv[8][136];
  const int t = threadIdx.x;
  const _Float16* fh = (const _Float16*)fused16;

#pragma unroll
  for (int it = 0; it < 4; ++it) {
    const int idx = it * 256 + t;
    const int ti = idx >> 7;
    const int e  = idx & 127;
    const int tok = tok0 + ti;
    const int h = e >> 4;
    const int lvl = (e >> 2) & 3;
    const int HW[4] = {64, 32, 16, 8};
    const int LS[4] = {0, 4096, 5120, 5376};
    const int Wl = HW[lvl];

    const float lg = (float)fh[(size_t)tok * 384 + 256 + e];
    float mx = lg;
#pragma unroll
    for (int o = 1; o < 16; o <<= 1) mx = fmaxf(mx, __shfl_xor(mx, o, 16));
    const float ex = __expf(lg - mx);
    float sm = ex;
#pragma unroll
    for (int o = 1; o < 16; o <<= 1) sm += __shfl_xor(sm, o, 16);
    const float a = ex / sm;

    const float ox = (float)fh[(size_t)tok * 384 + e * 2 + 0];
    const float oy = (float)fh[(size_t)tok * 384 + e * 2 + 1];
    const float rx = ref[(size_t)tok * 8 + lvl * 2 + 0];
    const float ry = ref[(size_t)tok * 8 + lvl * 2 + 1];
    const float x = rx * (float)Wl + ox - 0.5f;
    const float y = ry * (float)Wl + oy - 0.5f;
    const float x0f = floorf(x), y0f = floorf(y);
    const float fx = x - x0f, fy = y - y0f;
    const int x0 = (int)x0f, y0 = (int)y0f;

    const int xi1 = x0 + 1, yi1 = y0 + 1;
    const float wx0 = 1.f - fx, wx1 = fx, wy0 = 1.f - fy, wy1 = fy;
    const int xc0 = min(max(x0, 0), Wl - 1), xc1 = min(max(xi1, 0), Wl - 1);
    const int yc0 = min(max(y0, 0), Wl - 1), yc1 = min(max(yi1, 0), Wl - 1);
    const bool vx0 = (x0 >= 0) & (x0 < Wl), vx1 = (xi1 >= 0) & (xi1 < Wl);
    const bool vy0 = (y0 >= 0) & (y0 < Wl), vy1 = (yi1 >= 0) & (yi1 < Wl);
    half4v hw;
    hw.x = (_Float16)((vx0 & vy0) ? a * wx0 * wy0 : 0.f);
    hw.y = (_Float16)((vx1 & vy0) ? a * wx1 * wy0 : 0.f);
    hw.z = (_Float16)((vx0 & vy1) ? a * wx0 * wy1 : 0.f);
    hw.w = (_Float16)((vx1 & vy1) ? a * wx1 * wy1 : 0.f);
    const unsigned i00 = (unsigned)(LS[lvl] + yc0 * Wl + xc0);
    const unsigned i01 = (unsigned)(LS[lvl] + yc0 * Wl + xc1);
    const unsigned i10 = (unsigned)(LS[lvl] + yc1 * Wl + xc0);
    const unsigned i11 = (unsigned)(LS[lvl] + yc1 * Wl + xc1);
    uint2 io;
    io.x = i00 | (i01 << 16);
    io.y = i10 | (i11 << 16);
    const int sl = e + h;
    swv[ti][sl] = hw;
    siv[ti][sl] = io;
  }
  __syncthreads();

  const int wave = t >> 6, lane = t & 63;
  const int ti = wave * 2 + (lane >> 5);
  const int h = (lane >> 2) & 7, dg = lane & 3;
  const int tok = tok0 + ti;
  const int vbase = (tok0 / LQ_) * LQ_;
  const char* vb = (const char*)(value16 + (size_t)vbase * 256);
  const int laneoff = h * 64 + dg * 16;
  h2v a0 = {0, 0}, a1 = {0, 0}, a2 = {0, 0}, a3 = {0, 0};
  const int ebase = h * 17;

#pragma unroll 4
  for (int p = 0; p < 16; ++p) {
    const half4v hw = swv[ti][ebase + p];
    const uint2 io = siv[ti][ebase + p];
    const int o00 = (int)((io.x & 0xFFFFu) << 9) + laneoff;
    const int o01 = (int)((io.x >> 16) << 9) + laneoff;
    const int o10 = (int)((io.y & 0xFFFFu) << 9) + laneoff;
    const int o11 = (int)((io.y >> 16) << 9) + laneoff;
    const uint4 u0 = *(const uint4*)(vb + o00);
    const uint4 u1 = *(const uint4*)(vb + o01);
    const uint4 u2 = *(const uint4*)(vb + o10);
    const uint4 u3 = *(const uint4*)(vb + o11);
#define CORNER(U, WI) {                                            \
    const h2v w2 = __builtin_shufflevector(hw, hw, WI, WI);        \
    a0 += w2 * __builtin_bit_cast(h2v, U.x);                       \
    a1 += w2 * __builtin_bit_cast(h2v, U.y);                       \
    a2 += w2 * __builtin_bit_cast(h2v, U.z);                       \
    a3 += w2 * __builtin_bit_cast(h2v, U.w); }
    CORNER(u0, 0) CORNER(u1, 1) CORNER(u2, 2) CORNER(u3, 3)
#undef CORNER
  }

  uint4 o;
  o.x = __builtin_bit_cast(unsigned, a0);
  o.y = __builtin_bit_cast(unsigned, a1);
  o.z = __builtin_bit_cast(unsigned, a2);
  o.w = __builtin_bit_cast(unsigned, a3);
  *(uint4*)(att16 + (size_t)tok * 256 + h * 32 + dg * 8) = o;
}

// ---------------------------------------------------------------------------
extern "C" void kernel_launch(void* const* d_in, const int* in_sizes, int n_in,
                              void* d_out, int out_size, void* d_ws, size_t ws_size,
                              hipStream_t stream)
{
  const float* src   = (const float*)d_in[0];
  const float* pos   = (const float*)d_in[1];
  const float* ref   = (const float*)d_in[2];
  const float* Wv    = (const float*)d_in[5];
  const float* bv    = (const float*)d_in[6];
  const float* Woff  = (const float*)d_in[7];
  const float* boff  = (const float*)d_in[8];
  const float* Wattn = (const float*)d_in[9];
  const float* battn = (const float*)d_in[10];
  const float* Wout  = (const float*)d_in[11];
  const float* bout  = (const float*)d_in[12];
  const float* g1    = (const float*)d_in[13];
  const float* b1    = (const float*)d_in[14];
  const float* W1    = (const float*)d_in[15];
  const float* bb1   = (const float*)d_in[16];
  const float* W2    = (const float*)d_in[17];
  const float* bb2   = (const float*)d_in[18];
  const float* g3    = (const float*)d_in[19];
  const float* b3    = (const float*)d_in[20];

  float* out = (float*)d_out;
  char* ws = (char*)d_ws;
  const size_t M = M_TOK;

  unsigned short* value16 = (unsigned short*)ws;         // f16 M*256 (ends at samp)
  unsigned short* fused16 = (unsigned short*)(ws + M * 256 * 4);  // f16 M*384
  unsigned short* bufE = fused16 + M * 384;              // f16 M*256: s16 -> att16
  unsigned short* bufF = bufE + M * 256;                 // f16 M*256: q16 -> sxy16
  unsigned short* bufG = bufF + M * 256;                 // f16 weights (360448)

  unsigned short* WvT     = bufG + 0;
  unsigned short* WfusedT = bufG + 65536;
  unsigned short* WoutT   = bufG + 163840;
  unsigned short* W1T     = bufG + 229376;
  unsigned short* W2T     = bufG + 294912;

  const dim3 blk(256);

  prep_k<<<dim3(6848), blk, 0, stream>>>(src, pos, Wv, Woff, Wattn, Wout, W1, W2,
                                         bufE, bufF, bufG);
  // value16 = s16@WvT+bv ; fused16 = q16@[Woff|Wattn]+[boff|battn]
  gemm_qkv_k<<<dim3(850), blk, 0, stream>>>(bufE, bufF, WvT, WfusedT,
                                            bv, boff, battn, value16, fused16);
  // sampling (with in-kernel softmax) -> att16
  samp_k<<<dim3(2720), blk, 0, stream>>>(value16, fused16, ref, bufE);
  // sxy16 = f16(LN(att @ Wout + bout + src))
  gemm_ln_k<<<dim3(680), dim3(512), 0, stream>>>(bufE, WoutT, bout, src, nullptr,
                                                 g1, b1, nullptr, bufF);
  // out = LN(relu(sxy@W1+bb1)@W2 + bb2 + sxy)   [fused FFN]
  gemm_ffn_ln_k<<<dim3(680), dim3(512), 0, stream>>>(bufF, W1T, W2T, bb1, bb2,
                                                     g3, b3, out);
}